// Round 1
// baseline (218.891 us; speedup 1.0000x reference)
//
#include <hip/hip_runtime.h>
#include <stdint.h>

#define SLEN 2048
#define EMB  1024
#define NHEAD 16
#define HDIM  64
#define WINSZ 128

typedef __attribute__((ext_vector_type(8))) __bf16 bf16x8;
typedef __attribute__((ext_vector_type(4))) float  f32x4;

__device__ __forceinline__ unsigned short f2bf(float f) {
  union { float f; unsigned int u; } v;
  v.f = f;
  unsigned int r = v.u + 0x7FFFu + ((v.u >> 16) & 1u);
  return (unsigned short)(r >> 16);
}

// pack two floats to bf16 pair (round-half-up; inputs finite, in [0,1] for P)
__device__ __forceinline__ unsigned int pack_bf(float a, float b) {
  union { float f; unsigned int u; } x, y;
  x.f = a; y.f = b;
  return ((y.u + 0x8000u) & 0xFFFF0000u) | ((x.u + 0x8000u) >> 16);
}

// One fused convert for x, w_in, w_out -> contiguous bf16 region at ws base.
__global__ void cvt_all(const float* __restrict__ x,
                        const float* __restrict__ wi,
                        const float* __restrict__ wo,
                        unsigned short* __restrict__ dst) {
  const long n0 = 8388608, n1 = n0 + 3145728, n2 = n1 + 1048576;
  long i = ((long)blockIdx.x * 256 + threadIdx.x) * 4;
  if (i >= n2) return;
  const float* src; long off;
  if (i < n0)      { src = x;  off = i; }
  else if (i < n1) { src = wi; off = i - n0; }
  else             { src = wo; off = i - n1; }
  float4 f = *(const float4*)(src + off);
  ushort4 o;
  o.x = f2bf(f.x); o.y = f2bf(f.y); o.z = f2bf(f.z); o.w = f2bf(f.w);
  *(ushort4*)(dst + i) = o;
}

#define AS1(p) (const __attribute__((address_space(1))) unsigned int*)((const void*)(p))
#define AS3(p) (__attribute__((address_space(3))) unsigned int*)((void*)(p))

// C = A[M,K] * B[N,K]^T + bias, phased pipeline with counted vmcnt (T3+T4).
// Tile 128(M) x 256(N), BK=64, 512 thr = 8 waves (2M x 4N), 64x64 per wave.
// LDS: per buffer, per k-half regions A[128][32], B[256][32] (row stride
// 64 B -> ds_read_b128 frags are exactly 2-way bank-aliased = free, no
// swizzle; global_load_lds dest stays linear). 2 phases per K-tile (one per
// k-half); each phase stages 3 regions-worth (1xA + 2xB instr per wave) for
// the region consumed 3 phases later; steady-state wait = vmcnt(6), never 0.
// MODE 0: fp32 out at ldc. MODE 1 (qkv): cols <2048 -> bf16 at row-stride
// 2048; cols >=2048 (V) -> transposed into vt[b][h][d][s].
template <int MODE>
__global__ __launch_bounds__(512, 2) void gemm_nt(
    const unsigned short* __restrict__ A,
    const unsigned short* __restrict__ B,
    const float* __restrict__ bias,
    void* __restrict__ Cout,
    unsigned short* __restrict__ vt,
    int M, int N, int K, int ldc)
{
  // 96 KiB: A regions 2buf*2kh*4096, B regions 2buf*2kh*8192 (ushort units)
  __shared__ unsigned short lds[49152];
  const int tid  = threadIdx.x;
  const int wave = tid >> 6, lane = tid & 63;
  const int quad = lane >> 4, l16 = lane & 15;
  const int wm = (wave >> 2) * 64, wn = (wave & 3) * 64;

  // bijective XCD-aware block swizzle (nwg % 8 == 0 for both modes)
  const int nwgx = gridDim.x;
  const int nwg  = nwgx * gridDim.y;
  const int orig = blockIdx.y * nwgx + blockIdx.x;
  const int swz  = (orig & 7) * (nwg >> 3) + (orig >> 3);
  const long mBase = (long)(swz / nwgx) * 128;
  const long nBase = (long)(swz % nwgx) * 256;

  // staging: per instr, 16 rows x 32 cols (64 B/row, 16 B/lane)
  const int srow = lane >> 2, scol = (lane & 3) * 8;
  const unsigned short* Abase = A + (mBase + wave * 16 + srow) * (long)K + scol;
  const unsigned short* Bb0   = B + (nBase + (wave * 2 + 0) * 16 + srow) * (long)K + scol;
  const unsigned short* Bb1   = B + (nBase + (wave * 2 + 1) * 16 + srow) * (long)K + scol;
  const int aLd  = wave * 512;
  const int bLd0 = (wave * 2 + 0) * 512, bLd1 = (wave * 2 + 1) * 512;

#define AREG(b, kh) (lds + ((b) * 2 + (kh)) * 4096)
#define BREG(b, kh) (lds + 16384 + ((b) * 2 + (kh)) * 8192)
#define STAGE(TT, KH) do {                                                           \
    const int _b = (TT) & 1;                                                         \
    const long _kc = (long)(TT) * 64 + (KH) * 32;                                    \
    __builtin_amdgcn_global_load_lds(AS1(Abase + _kc), AS3(AREG(_b, KH) + aLd), 16, 0, 0);  \
    __builtin_amdgcn_global_load_lds(AS1(Bb0 + _kc),   AS3(BREG(_b, KH) + bLd0), 16, 0, 0); \
    __builtin_amdgcn_global_load_lds(AS1(Bb1 + _kc),   AS3(BREG(_b, KH) + bLd1), 16, 0, 0); \
  } while (0)

  f32x4 acc[4][4];
#pragma unroll
  for (int i = 0; i < 4; ++i)
#pragma unroll
    for (int j = 0; j < 4; ++j)
#pragma unroll
      for (int r = 0; r < 4; ++r) acc[i][j][r] = 0.f;

  const int NT = K >> 6;

  // prologue: 3 phases' worth in flight, then enter uniform steady state
  STAGE(0, 0); STAGE(0, 1); STAGE(1, 0);
  asm volatile("s_waitcnt vmcnt(6)" ::: "memory");
  __builtin_amdgcn_s_barrier();

  for (int T = 0; T < NT; ++T) {
    const int buf = T & 1;
    // ---------- phase k0: cols [T*64, T*64+32) ----------
    {
      const unsigned short* Ar = AREG(buf, 0);
      const unsigned short* Br = BREG(buf, 0);
      bf16x8 aF[4], bF[4];
#pragma unroll
      for (int i = 0; i < 4; ++i)
        aF[i] = *(const bf16x8*)(Ar + (wm + i * 16 + l16) * 32 + quad * 8);
#pragma unroll
      for (int j = 0; j < 4; ++j)
        bF[j] = *(const bf16x8*)(Br + (wn + j * 16 + l16) * 32 + quad * 8);
      if (T + 1 < NT) {
        STAGE(T + 1, 1);   // consumed 3 phases later; dest buf (T+1)&1 idle
        asm volatile("s_waitcnt vmcnt(6)" ::: "memory");
      } else {
        asm volatile("s_waitcnt vmcnt(0)" ::: "memory");
      }
      __builtin_amdgcn_s_barrier();
      asm volatile("s_waitcnt lgkmcnt(0)" ::: "memory");
      __builtin_amdgcn_sched_barrier(0);
      __builtin_amdgcn_s_setprio(1);
#pragma unroll
      for (int i = 0; i < 4; ++i)
#pragma unroll
        for (int j = 0; j < 4; ++j)
          acc[i][j] = __builtin_amdgcn_mfma_f32_16x16x32_bf16(aF[i], bF[j], acc[i][j], 0, 0, 0);
      __builtin_amdgcn_s_setprio(0);
      __builtin_amdgcn_s_barrier();
    }
    // ---------- phase k1: cols [T*64+32, T*64+64) ----------
    {
      const unsigned short* Ar = AREG(buf, 1);
      const unsigned short* Br = BREG(buf, 1);
      bf16x8 aF[4], bF[4];
#pragma unroll
      for (int i = 0; i < 4; ++i)
        aF[i] = *(const bf16x8*)(Ar + (wm + i * 16 + l16) * 32 + quad * 8);
#pragma unroll
      for (int j = 0; j < 4; ++j)
        bF[j] = *(const bf16x8*)(Br + (wn + j * 16 + l16) * 32 + quad * 8);
      if (T + 2 < NT) {
        STAGE(T + 2, 0);   // this buffer's k0 regions: dead since phase k0
        asm volatile("s_waitcnt vmcnt(6)" ::: "memory");
      } else if (T + 1 < NT) {
        asm volatile("s_waitcnt vmcnt(3)" ::: "memory");
      }
      __builtin_amdgcn_s_barrier();
      asm volatile("s_waitcnt lgkmcnt(0)" ::: "memory");
      __builtin_amdgcn_sched_barrier(0);
      __builtin_amdgcn_s_setprio(1);
#pragma unroll
      for (int i = 0; i < 4; ++i)
#pragma unroll
        for (int j = 0; j < 4; ++j)
          acc[i][j] = __builtin_amdgcn_mfma_f32_16x16x32_bf16(aF[i], bF[j], acc[i][j], 0, 0, 0);
      __builtin_amdgcn_s_setprio(0);
      __builtin_amdgcn_s_barrier();
    }
  }
#undef STAGE
#undef AREG
#undef BREG

  if (MODE == 1 && nBase >= 2048) {
    // V block: write transposed into vt[b][h][d][s]; r=0..3 -> s contiguous
#pragma unroll
    for (int j = 0; j < 4; ++j) {
      const int nG = (int)nBase + wn + j * 16 + l16;
      const float bv = bias[nG];
      const int hd = nG - 2048;
      const int hh = hd >> 6, dd = hd & 63;
#pragma unroll
      for (int i = 0; i < 4; ++i) {
        const int mG0 = (int)mBase + wm + i * 16 + quad * 4;
        const int bb = mG0 >> 11, ss = mG0 & 2047;
        ushort4 o;
        o.x = f2bf(acc[i][j][0] + bv);
        o.y = f2bf(acc[i][j][1] + bv);
        o.z = f2bf(acc[i][j][2] + bv);
        o.w = f2bf(acc[i][j][3] + bv);
        *(ushort4*)(vt + (((long)(bb * NHEAD + hh)) * HDIM + dd) * SLEN + ss) = o;
      }
    }
  } else {
#pragma unroll
    for (int j = 0; j < 4; ++j) {
      const long nG = nBase + wn + j * 16 + l16;
      const float bv = bias[nG];
#pragma unroll
      for (int i = 0; i < 4; ++i)
#pragma unroll
        for (int r = 0; r < 4; ++r) {
          const long mG = mBase + wm + i * 16 + quad * 4 + r;
          const float v = acc[i][j][r] + bv;
          if (MODE == 1) ((unsigned short*)Cout)[mG * ldc + nG] = f2bf(v);
          else           ((float*)Cout)[mG * ldc + nG] = v;
        }
    }
  }
}

// Banded-causal flash attention, S^T orientation, batched softmax.
// 128-query blocks (512 thr, 8 waves). qk: [B*S][2048] bf16 (Q|K),
// vT: [B*H][64][2048]. K and V staged in XOR-swizzled LDS (GEMM-proven
// conflict-free geometry: 128B-multiple row stride + 16B-chunk XOR).
__global__ __launch_bounds__(512, 4) void local_attn(
    const unsigned short* __restrict__ qk,
    const unsigned short* __restrict__ vT,
    unsigned short* __restrict__ outw)
{
  const int qb = blockIdx.x;   // 128-query tile
  const int h  = blockIdx.y;
  const int b  = blockIdx.z;
  const int tid = threadIdx.x;
  const int wave = tid >> 6, lane = tid & 63;
  const int quad = lane >> 4, l16 = lane & 15;

  __shared__ unsigned short Klds[256 * 64];   // [key][chunk ^ (key&7)]
  __shared__ unsigned short Vlds[64 * 256];   // [d][chunk ^ (d&7)] along key

  const int kwin0 = qb * 128 - WINSZ;         // global key of local key 0

  // --- K staging via global_load_lds (swizzled, clamped rows) ---
  {
    const int kr = lane >> 3, kc = lane & 7;
    const long colOff = 1024 + h * HDIM + ((kc ^ kr) * 8);
#pragma unroll
    for (int t = 0; t < 4; ++t) {
      const int u = wave * 4 + t;                 // unit of 8 keys (32 units)
      const int sk = max(kwin0 + u * 8 + kr, 0);  // clamp; junk masked later
      const unsigned short* g = qk + (long)(b * SLEN + sk) * 2048 + colOff;
      __builtin_amdgcn_global_load_lds(AS1(g), AS3(Klds + u * 512), 16, 0, 0);
    }
  }
  // --- V^T staging: coalesced reads from vT, XOR-swizzled LDS writes ---
  {
    const unsigned short* vbase = vT + ((long)(b * NHEAD + h)) * HDIM * SLEN;
#pragma unroll
    for (int t = 0; t < 4; ++t) {
      const int c = t * 512 + tid;          // [0, 2048): 64 d x 32 chunks
      const int d = c >> 5, k8 = c & 31;
      const int s0 = max(kwin0 + k8 * 8, 0);
      uint4 v = *(const uint4*)(vbase + (long)d * SLEN + s0);
      *(uint4*)(Vlds + d * 256 + ((k8 ^ (d & 7)) * 8)) = v;
    }
  }

  // Q fragments (B-operand): 16 queries per wave
  const int q0 = qb * 128 + wave * 16;
  const long qrow = (long)(b * SLEN + q0 + l16) * 2048 + h * HDIM;
  const bf16x8 qB0 = *(const bf16x8*)(qk + qrow + quad * 8);
  const bf16x8 qB1 = *(const bf16x8*)(qk + qrow + 32 + quad * 8);

  __syncthreads();

  // --- QK^T (S^T orientation): all 5 x 32 keys ---
  const int lbase = (wave * 16) & ~31;
  const int kx = l16 & 7;
  const int a0 = (quad ^ kx) * 8;
  const int a1 = ((4 + quad) ^ kx) * 8;
  f32x4 sc[5][2];
#pragma unroll
  for (int it = 0; it < 5; ++it) {
    const int l0 = lbase + it * 32;
#pragma unroll
    for (int half = 0; half < 2; ++half) {
      const unsigned short* kr_ = Klds + (l0 + half * 16 + l16) * 64;
      const bf16x8 kA0 = *(const bf16x8*)(kr_ + a0);
      const bf16x8 kA1 = *(const bf16x8*)(kr_ + a1);
      f32x4 s;
#pragma unroll
      for (int r = 0; r < 4; ++r) s[r] = 0.f;
      s = __builtin_amdgcn_mfma_f32_16x16x32_bf16(kA0, qB0, s, 0, 0, 0);
      s = __builtin_amdgcn_mfma_f32_16x16x32_bf16(kA1, qB1, s, 0, 0, 0);
      sc[it][half] = s;   // row = key_local = quad*4+r, col = query = l16
    }
  }

  // --- mask + scale; batched softmax (reduce over quads: 2 shfl steps) ---
  // Valid local keys for query: [qlocal - WINSZ, qlocal], clipped below
  // -kwin0 when staging clamped (qb==0 -> 128).
  const int qlocal = WINSZ + wave * 16 + l16;       // own query, local coords
  const int lo = max(wave * 16 + l16, kwin0 < 0 ? -kwin0 : 0);
  const int kb = lbase + quad * 4;
  float m = -3.0e38f;
#pragma unroll
  for (int it = 0; it < 5; ++it)
#pragma unroll
    for (int half = 0; half < 2; ++half)
#pragma unroll
      for (int r = 0; r < 4; ++r) {
        const int kl = kb + it * 32 + half * 16 + r;
        float v = sc[it][half][r] * 0.125f;
        v = (kl >= lo && kl <= qlocal) ? v : -3.0e38f;
        sc[it][half][r] = v;
        m = fmaxf(m, v);
      }
  m = fmaxf(m, __shfl_xor(m, 16, 64));
  m = fmaxf(m, __shfl_xor(m, 32, 64));

  float lsum = 0.f;
#pragma unroll
  for (int it = 0; it < 5; ++it)
#pragma unroll
    for (int half = 0; half < 2; ++half)
#pragma unroll
      for (int r = 0; r < 4; ++r) {
        const float e = __expf(sc[it][half][r] - m);
        sc[it][half][r] = e;
        lsum += e;
      }
  lsum += __shfl_xor(lsum, 16, 64);
  lsum += __shfl_xor(lsum, 32, 64);
  const float invl = 1.0f / lsum;

  // --- PV: O^T = V^T * P^T; P^T B-frag assembled via shuffles ---
  f32x4 Oacc[4];
#pragma unroll
  for (int dt = 0; dt < 4; ++dt)
#pragma unroll
    for (int r = 0; r < 4; ++r) Oacc[dt][r] = 0.f;

#pragma unroll
  for (int it = 0; it < 5; ++it) {
    const int l0 = lbase + it * 32;
    // pack this lane's 8 P values (4 per half) into bf16 pairs
    const unsigned int u0 = pack_bf(sc[it][0][0], sc[it][0][1]);
    const unsigned int u1 = pack_bf(sc[it][0][2], sc[it][0][3]);
    const unsigned int u2 = pack_bf(sc[it][1][0], sc[it][1][1]);
    const unsigned int u3 = pack_bf(sc[it][1][2], sc[it][1][3]);
    // gather B-frag: lane needs keys quad*8 + [0..7] of query l16
    unsigned int breg[4];
#pragma unroll
    for (int r = 0; r < 4; ++r) {
      const int srcl = ((quad & 1) * 2 + (r >> 1)) * 16 + l16;
      const unsigned int ga = __shfl((int)((r & 1) ? u1 : u0), srcl, 64);
      const unsigned int gb = __shfl((int)((r & 1) ? u3 : u2), srcl, 64);
      breg[r] = (quad >> 1) ? gb : ga;
    }
    union { unsigned int u[4]; bf16x8 v; } pB;
    pB.u[0] = breg[0]; pB.u[1] = breg[1]; pB.u[2] = breg[2]; pB.u[3] = breg[3];

    const int chBase = (l0 >> 3);                 // multiple of 4
#pragma unroll
    for (int dt = 0; dt < 4; ++dt) {
      const int ch = (chBase + quad) ^ kx;        // kx = l16&7 = d&7
      const bf16x8 vA = *(const bf16x8*)(Vlds + (dt * 16 + l16) * 256 + ch * 8);
      Oacc[dt] = __builtin_amdgcn_mfma_f32_16x16x32_bf16(vA, pB.v, Oacc[dt], 0, 0, 0);
    }
  }

  // --- epilogue: O^T C-layout; r=0..3 contiguous -> packed ushort4 stores ---
  const long obase = (long)(b * SLEN + q0 + l16) * EMB + h * HDIM;
#pragma unroll
  for (int dt = 0; dt < 4; ++dt) {
    ushort4 o;
    o.x = f2bf(Oacc[dt][0] * invl);
    o.y = f2bf(Oacc[dt][1] * invl);
    o.z = f2bf(Oacc[dt][2] * invl);
    o.w = f2bf(Oacc[dt][3] * invl);
    *(ushort4*)(outw + obase + dt * 16 + quad * 4) = o;
  }
}

extern "C" void kernel_launch(void* const* d_in, const int* in_sizes, int n_in,
                              void* d_out, int out_size, void* d_ws, size_t ws_size,
                              hipStream_t stream) {
  const float* x     = (const float*)d_in[0];
  const float* w_in  = (const float*)d_in[1];
  const float* b_in  = (const float*)d_in[2];
  const float* w_out = (const float*)d_in[3];
  const float* b_out = (const float*)d_in[4];
  float* out = (float*)d_out;

  char* ws = (char*)d_ws;
  unsigned short* xb    = (unsigned short*)(ws + 0);          // 16,777,216
  unsigned short* winb  = (unsigned short*)(ws + 16777216);   //  6,291,456
  unsigned short* woutb = (unsigned short*)(ws + 23068672);   //  2,097,152
  unsigned short* qkb   = (unsigned short*)(ws + 25165824);   // 8192x2048 bf16 = 33,554,432
  unsigned short* attn  = (unsigned short*)(ws + 58720256);   // 16,777,216
  unsigned short* vT    = (unsigned short*)(ws + 75497472);   // 16,777,216  (total 92,274,688)

  // fused converts: dst regions are contiguous (xb|winb|woutb)
  const long ncv = 8388608 + 3145728 + 1048576;               // 12,582,912
  cvt_all<<<(int)(ncv / 1024), 256, 0, stream>>>(x, w_in, w_out, xb);

  // qkv projection: Q,K -> qkb (stride 2048); V -> vT transposed
  gemm_nt<1><<<dim3(3072 / 256, 8192 / 128), 512, 0, stream>>>(
      xb, winb, b_in, (void*)qkb, vT, 8192, 3072, 1024, 2048);

  local_attn<<<dim3(SLEN / 128, NHEAD, 4), 512, 0, stream>>>(qkb, vT, attn);

  gemm_nt<0><<<dim3(1024 / 256, 8192 / 128), 512, 0, stream>>>(
      attn, woutb, b_out, (void*)out, nullptr, 8192, 1024, 1024, 1024);
}

// Round 3
// 203.333 us; speedup vs baseline: 1.0765x; 1.0765x over previous
//
#include <hip/hip_runtime.h>
#include <stdint.h>

#define SLEN 2048
#define EMB  1024
#define NHEAD 16
#define HDIM  64
#define WINSZ 128

typedef __attribute__((ext_vector_type(8))) __bf16 bf16x8;
typedef __attribute__((ext_vector_type(4))) float  f32x4;

__device__ __forceinline__ unsigned short f2bf(float f) {
  union { float f; unsigned int u; } v;
  v.f = f;
  unsigned int r = v.u + 0x7FFFu + ((v.u >> 16) & 1u);
  return (unsigned short)(r >> 16);
}

// pack two floats to bf16 pair (round-half-up; inputs finite, in [0,1] for P)
__device__ __forceinline__ unsigned int pack_bf(float a, float b) {
  union { float f; unsigned int u; } x, y;
  x.f = a; y.f = b;
  return ((y.u + 0x8000u) & 0xFFFF0000u) | ((x.u + 0x8000u) >> 16);
}

// One fused convert for x, w_in, w_out -> contiguous bf16 region at ws base.
__global__ void cvt_all(const float* __restrict__ x,
                        const float* __restrict__ wi,
                        const float* __restrict__ wo,
                        unsigned short* __restrict__ dst) {
  const long n0 = 8388608, n1 = n0 + 3145728, n2 = n1 + 1048576;
  long i = ((long)blockIdx.x * 256 + threadIdx.x) * 4;
  if (i >= n2) return;
  const float* src; long off;
  if (i < n0)      { src = x;  off = i; }
  else if (i < n1) { src = wi; off = i - n0; }
  else             { src = wo; off = i - n1; }
  float4 f = *(const float4*)(src + off);
  ushort4 o;
  o.x = f2bf(f.x); o.y = f2bf(f.y); o.z = f2bf(f.z); o.w = f2bf(f.w);
  *(ushort4*)(dst + i) = o;
}

#define AS1(p) (const __attribute__((address_space(1))) unsigned int*)((const void*)(p))
#define AS3(p) (__attribute__((address_space(3))) unsigned int*)((void*)(p))

// C = A[M,K] * B[N,K]^T + bias.  Tile 128(M) x 256(N), BK=64, 512 thr =
// 8 waves (2M x 4N), 64x64 per wave.  LDS: triple-buffered full K-tiles,
// A[128][64] + B[256][64] per buffer (row stride 128 B, chunk-XOR swizzle
// (chunk ^ (row&7)) -- the round-0 geometry that measured ZERO bank
// conflicts; global_load_lds dest linear, source pre-swizzled).
// Pipeline: tile T+2 staged during tile T (3 loads/wave/phase), steady
// state s_waitcnt vmcnt(6) (tile T+1's 6 loads stay in flight across the
// barrier), ONE barrier per K-tile.  MODE 0: fp32 out at ldc.  MODE 1
// (qkv): cols <2048 -> bf16 at row-stride 2048; cols >=2048 (V) ->
// transposed into vt[b][h][d][s].
template <int MODE>
__global__ __launch_bounds__(512, 2) void gemm_nt(
    const unsigned short* __restrict__ A,
    const unsigned short* __restrict__ B,
    const float* __restrict__ bias,
    void* __restrict__ Cout,
    unsigned short* __restrict__ vt,
    int M, int N, int K, int ldc)
{
  // 3 buffers x (A 8192 + B 16384) ushorts = 144 KiB
  __shared__ unsigned short lds[73728];
  const int tid  = threadIdx.x;
  const int wave = tid >> 6, lane = tid & 63;
  const int quad = lane >> 4, l16 = lane & 15;
  const int wm = (wave >> 2) * 64, wn = (wave & 3) * 64;
  const int swz = l16 & 7;

  // bijective XCD-aware block swizzle (nwg % 8 == 0 for both modes)
  const int nwgx = gridDim.x;
  const int nwg  = nwgx * gridDim.y;
  const int orig = blockIdx.y * nwgx + blockIdx.x;
  const int bswz = (orig & 7) * (nwg >> 3) + (orig >> 3);
  const long mBase = (long)(bswz / nwgx) * 128;
  const long nBase = (long)(bswz % nwgx) * 256;

  // staging: each instr covers 8 rows x 64 cols; source col pre-swizzled
  const int lr  = lane >> 3;
  const int lks = ((lane & 7) ^ lr) * 8;
  const unsigned short* Abase = A + (mBase + lr) * (long)K + lks;
  const unsigned short* Bbase = B + (nBase + lr) * (long)K + lks;

  // H==0: A rows [w*16,w*16+8) + B rows [w*32,w*32+16)
  // H==1: A rows [w*16+8,..)   + B rows [w*32+16,w*32+32)
#define STAGE3(TT, dstOff, H) do {                                                     \
    const long _kc = (long)(TT) * 64;                                                  \
    const int _ar = wave * 16 + (H) * 8;                                               \
    const int _br = wave * 32 + (H) * 16;                                              \
    __builtin_amdgcn_global_load_lds(AS1(Abase + (long)_ar * K + _kc),                 \
                                     AS3(lds + (dstOff) + _ar * 64), 16, 0, 0);        \
    __builtin_amdgcn_global_load_lds(AS1(Bbase + (long)_br * K + _kc),                 \
                                     AS3(lds + (dstOff) + 8192 + _br * 64), 16, 0, 0); \
    __builtin_amdgcn_global_load_lds(AS1(Bbase + (long)(_br + 8) * K + _kc),           \
                                     AS3(lds + (dstOff) + 8192 + (_br + 8) * 64), 16, 0, 0); \
  } while (0)

  f32x4 acc[4][4];
#pragma unroll
  for (int i = 0; i < 4; ++i)
#pragma unroll
    for (int j = 0; j < 4; ++j)
#pragma unroll
      for (int r = 0; r < 4; ++r) acc[i][j][r] = 0.f;

  const int NT = K >> 6;   // >= 3

  // prologue: tiles 0 and 1 fully staged (12 loads/wave)
  STAGE3(0, 0, 0); STAGE3(0, 0, 1);
  STAGE3(1, 24576, 0); STAGE3(1, 24576, 1);

  int curOff = 0, stgOff = 49152;
  for (int T = 0; T < NT; ++T) {
    // tile-entry sync: own loads of tile T drained (allow T+1's 6 in
    // flight), then rendezvous -> all waves' tile-T loads resident.
    if (T + 1 < NT) asm volatile("s_waitcnt vmcnt(6)" ::: "memory");
    else            asm volatile("s_waitcnt vmcnt(0)" ::: "memory");
    __builtin_amdgcn_s_barrier();
    __builtin_amdgcn_sched_barrier(0);

    const unsigned short* Ar = lds + curOff;
    const unsigned short* Br = lds + curOff + 8192;
    const bool doStage = (T + 2 < NT);

#pragma unroll
    for (int s = 0; s < 2; ++s) {
      bf16x8 aF[4], bF[4];
#pragma unroll
      for (int i = 0; i < 4; ++i)
        aF[i] = *(const bf16x8*)(Ar + (wm + i * 16 + l16) * 64 + (((s * 4 + quad) ^ swz) * 8));
#pragma unroll
      for (int j = 0; j < 4; ++j)
        bF[j] = *(const bf16x8*)(Br + (wn + j * 16 + l16) * 64 + (((s * 4 + quad) ^ swz) * 8));
      if (doStage) STAGE3(T + 2, stgOff, s);   // dest buf holds dead tile T-1
      asm volatile("s_waitcnt lgkmcnt(0)" ::: "memory");
      __builtin_amdgcn_sched_barrier(0);
      __builtin_amdgcn_s_setprio(1);
#pragma unroll
      for (int i = 0; i < 4; ++i)
#pragma unroll
        for (int j = 0; j < 4; ++j)
          acc[i][j] = __builtin_amdgcn_mfma_f32_16x16x32_bf16(aF[i], bF[j], acc[i][j], 0, 0, 0);
      __builtin_amdgcn_s_setprio(0);
    }
    curOff = (curOff == 49152) ? 0 : curOff + 24576;
    stgOff = (stgOff == 49152) ? 0 : stgOff + 24576;
  }
#undef STAGE3

  if (MODE == 1 && nBase >= 2048) {
    // V block: write transposed into vt[b][h][d][s]; r=0..3 -> s contiguous
#pragma unroll
    for (int j = 0; j < 4; ++j) {
      const int nG = (int)nBase + wn + j * 16 + l16;
      const float bv = bias[nG];
      const int hd = nG - 2048;
      const int hh = hd >> 6, dd = hd & 63;
#pragma unroll
      for (int i = 0; i < 4; ++i) {
        const int mG0 = (int)mBase + wm + i * 16 + quad * 4;
        const int bb = mG0 >> 11, ss = mG0 & 2047;
        ushort4 o;
        o.x = f2bf(acc[i][j][0] + bv);
        o.y = f2bf(acc[i][j][1] + bv);
        o.z = f2bf(acc[i][j][2] + bv);
        o.w = f2bf(acc[i][j][3] + bv);
        *(ushort4*)(vt + (((long)(bb * NHEAD + hh)) * HDIM + dd) * SLEN + ss) = o;
      }
    }
  } else {
#pragma unroll
    for (int j = 0; j < 4; ++j) {
      const long nG = nBase + wn + j * 16 + l16;
      const float bv = bias[nG];
#pragma unroll
      for (int i = 0; i < 4; ++i)
#pragma unroll
        for (int r = 0; r < 4; ++r) {
          const long mG = mBase + wm + i * 16 + quad * 4 + r;
          const float v = acc[i][j][r] + bv;
          if (MODE == 1) ((unsigned short*)Cout)[mG * ldc + nG] = f2bf(v);
          else           ((float*)Cout)[mG * ldc + nG] = v;
        }
    }
  }
}

// Banded-causal flash attention, S^T orientation, batched softmax.
// 128-query blocks (512 thr, 8 waves). qk: [B*S][2048] bf16 (Q|K),
// vT: [B*H][64][2048]. K and V staged in XOR-swizzled LDS (GEMM-proven
// conflict-free geometry: 128B-multiple row stride + 16B-chunk XOR).
__global__ __launch_bounds__(512, 4) void local_attn(
    const unsigned short* __restrict__ qk,
    const unsigned short* __restrict__ vT,
    unsigned short* __restrict__ outw)
{
  const int qb = blockIdx.x;   // 128-query tile
  const int h  = blockIdx.y;
  const int b  = blockIdx.z;
  const int tid = threadIdx.x;
  const int wave = tid >> 6, lane = tid & 63;
  const int quad = lane >> 4, l16 = lane & 15;

  __shared__ unsigned short Klds[256 * 64];   // [key][chunk ^ (key&7)]
  __shared__ unsigned short Vlds[64 * 256];   // [d][chunk ^ (d&7)] along key

  const int kwin0 = qb * 128 - WINSZ;         // global key of local key 0

  // --- K staging via global_load_lds (swizzled, clamped rows) ---
  {
    const int kr = lane >> 3, kc = lane & 7;
    const long colOff = 1024 + h * HDIM + ((kc ^ kr) * 8);
#pragma unroll
    for (int t = 0; t < 4; ++t) {
      const int u = wave * 4 + t;                 // unit of 8 keys (32 units)
      const int sk = max(kwin0 + u * 8 + kr, 0);  // clamp; junk masked later
      const unsigned short* g = qk + (long)(b * SLEN + sk) * 2048 + colOff;
      __builtin_amdgcn_global_load_lds(AS1(g), AS3(Klds + u * 512), 16, 0, 0);
    }
  }
  // --- V^T staging: coalesced reads from vT, XOR-swizzled LDS writes ---
  {
    const unsigned short* vbase = vT + ((long)(b * NHEAD + h)) * HDIM * SLEN;
#pragma unroll
    for (int t = 0; t < 4; ++t) {
      const int c = t * 512 + tid;          // [0, 2048): 64 d x 32 chunks
      const int d = c >> 5, k8 = c & 31;
      const int s0 = max(kwin0 + k8 * 8, 0);
      uint4 v = *(const uint4*)(vbase + (long)d * SLEN + s0);
      *(uint4*)(Vlds + d * 256 + ((k8 ^ (d & 7)) * 8)) = v;
    }
  }

  // Q fragments (B-operand): 16 queries per wave
  const int q0 = qb * 128 + wave * 16;
  const long qrow = (long)(b * SLEN + q0 + l16) * 2048 + h * HDIM;
  const bf16x8 qB0 = *(const bf16x8*)(qk + qrow + quad * 8);
  const bf16x8 qB1 = *(const bf16x8*)(qk + qrow + 32 + quad * 8);

  __syncthreads();

  // --- QK^T (S^T orientation): all 5 x 32 keys ---
  const int lbase = (wave * 16) & ~31;
  const int kx = l16 & 7;
  const int a0 = (quad ^ kx) * 8;
  const int a1 = ((4 + quad) ^ kx) * 8;
  f32x4 sc[5][2];
#pragma unroll
  for (int it = 0; it < 5; ++it) {
    const int l0 = lbase + it * 32;
#pragma unroll
    for (int half = 0; half < 2; ++half) {
      const unsigned short* kr_ = Klds + (l0 + half * 16 + l16) * 64;
      const bf16x8 kA0 = *(const bf16x8*)(kr_ + a0);
      const bf16x8 kA1 = *(const bf16x8*)(kr_ + a1);
      f32x4 s;
#pragma unroll
      for (int r = 0; r < 4; ++r) s[r] = 0.f;
      s = __builtin_amdgcn_mfma_f32_16x16x32_bf16(kA0, qB0, s, 0, 0, 0);
      s = __builtin_amdgcn_mfma_f32_16x16x32_bf16(kA1, qB1, s, 0, 0, 0);
      sc[it][half] = s;   // row = key_local = quad*4+r, col = query = l16
    }
  }

  // --- mask + scale; batched softmax (reduce over quads: 2 shfl steps) ---
  // Valid local keys for query: [qlocal - WINSZ, qlocal], clipped below
  // -kwin0 when staging clamped (qb==0 -> 128).
  const int qlocal = WINSZ + wave * 16 + l16;       // own query, local coords
  const int lo = max(wave * 16 + l16, kwin0 < 0 ? -kwin0 : 0);
  const int kb = lbase + quad * 4;
  float m = -3.0e38f;
#pragma unroll
  for (int it = 0; it < 5; ++it)
#pragma unroll
    for (int half = 0; half < 2; ++half)
#pragma unroll
      for (int r = 0; r < 4; ++r) {
        const int kl = kb + it * 32 + half * 16 + r;
        float v = sc[it][half][r] * 0.125f;
        v = (kl >= lo && kl <= qlocal) ? v : -3.0e38f;
        sc[it][half][r] = v;
        m = fmaxf(m, v);
      }
  m = fmaxf(m, __shfl_xor(m, 16, 64));
  m = fmaxf(m, __shfl_xor(m, 32, 64));

  float lsum = 0.f;
#pragma unroll
  for (int it = 0; it < 5; ++it)
#pragma unroll
    for (int half = 0; half < 2; ++half)
#pragma unroll
      for (int r = 0; r < 4; ++r) {
        const float e = __expf(sc[it][half][r] - m);
        sc[it][half][r] = e;
        lsum += e;
      }
  lsum += __shfl_xor(lsum, 16, 64);
  lsum += __shfl_xor(lsum, 32, 64);
  const float invl = 1.0f / lsum;

  // --- PV: O^T = V^T * P^T; P^T B-frag assembled via shuffles ---
  f32x4 Oacc[4];
#pragma unroll
  for (int dt = 0; dt < 4; ++dt)
#pragma unroll
    for (int r = 0; r < 4; ++r) Oacc[dt][r] = 0.f;

#pragma unroll
  for (int it = 0; it < 5; ++it) {
    const int l0 = lbase + it * 32;
    // pack this lane's 8 P values (4 per half) into bf16 pairs
    const unsigned int u0 = pack_bf(sc[it][0][0], sc[it][0][1]);
    const unsigned int u1 = pack_bf(sc[it][0][2], sc[it][0][3]);
    const unsigned int u2 = pack_bf(sc[it][1][0], sc[it][1][1]);
    const unsigned int u3 = pack_bf(sc[it][1][2], sc[it][1][3]);
    // gather B-frag: lane needs keys quad*8 + [0..7] of query l16
    unsigned int breg[4];
#pragma unroll
    for (int r = 0; r < 4; ++r) {
      const int srcl = ((quad & 1) * 2 + (r >> 1)) * 16 + l16;
      const unsigned int ga = __shfl((int)((r & 1) ? u1 : u0), srcl, 64);
      const unsigned int gb = __shfl((int)((r & 1) ? u3 : u2), srcl, 64);
      breg[r] = (quad >> 1) ? gb : ga;
    }
    union { unsigned int u[4]; bf16x8 v; } pB;
    pB.u[0] = breg[0]; pB.u[1] = breg[1]; pB.u[2] = breg[2]; pB.u[3] = breg[3];

    const int chBase = (l0 >> 3);                 // multiple of 4
#pragma unroll
    for (int dt = 0; dt < 4; ++dt) {
      const int ch = (chBase + quad) ^ kx;        // kx = l16&7 = d&7
      const bf16x8 vA = *(const bf16x8*)(Vlds + (dt * 16 + l16) * 256 + ch * 8);
      Oacc[dt] = __builtin_amdgcn_mfma_f32_16x16x32_bf16(vA, pB.v, Oacc[dt], 0, 0, 0);
    }
  }

  // --- epilogue: O^T C-layout; r=0..3 contiguous -> packed ushort4 stores ---
  const long obase = (long)(b * SLEN + q0 + l16) * EMB + h * HDIM;
#pragma unroll
  for (int dt = 0; dt < 4; ++dt) {
    ushort4 o;
    o.x = f2bf(Oacc[dt][0] * invl);
    o.y = f2bf(Oacc[dt][1] * invl);
    o.z = f2bf(Oacc[dt][2] * invl);
    o.w = f2bf(Oacc[dt][3] * invl);
    *(ushort4*)(outw + obase + dt * 16 + quad * 4) = o;
  }
}

extern "C" void kernel_launch(void* const* d_in, const int* in_sizes, int n_in,
                              void* d_out, int out_size, void* d_ws, size_t ws_size,
                              hipStream_t stream) {
  const float* x     = (const float*)d_in[0];
  const float* w_in  = (const float*)d_in[1];
  const float* b_in  = (const float*)d_in[2];
  const float* w_out = (const float*)d_in[3];
  const float* b_out = (const float*)d_in[4];
  float* out = (float*)d_out;

  char* ws = (char*)d_ws;
  unsigned short* xb    = (unsigned short*)(ws + 0);          // 16,777,216
  unsigned short* winb  = (unsigned short*)(ws + 16777216);   //  6,291,456
  unsigned short* woutb = (unsigned short*)(ws + 23068672);   //  2,097,152
  unsigned short* qkb   = (unsigned short*)(ws + 25165824);   // 8192x2048 bf16 = 33,554,432
  unsigned short* attn  = (unsigned short*)(ws + 58720256);   // 16,777,216
  unsigned short* vT    = (unsigned short*)(ws + 75497472);   // 16,777,216  (total 92,274,688)

  // fused converts: dst regions are contiguous (xb|winb|woutb)
  const long ncv = 8388608 + 3145728 + 1048576;               // 12,582,912
  cvt_all<<<(int)(ncv / 1024), 256, 0, stream>>>(x, w_in, w_out, xb);

  // qkv projection: Q,K -> qkb (stride 2048); V -> vT transposed
  gemm_nt<1><<<dim3(3072 / 256, 8192 / 128), 512, 0, stream>>>(
      xb, winb, b_in, (void*)qkb, vT, 8192, 3072, 1024, 2048);

  local_attn<<<dim3(SLEN / 128, NHEAD, 4), 512, 0, stream>>>(qkb, vT, attn);

  gemm_nt<0><<<dim3(1024 / 256, 8192 / 128), 512, 0, stream>>>(
      attn, woutb, b_out, (void*)out, nullptr, 8192, 1024, 1024, 1024);
}